// Round 9
// baseline (558.134 us; speedup 1.0000x reference)
//
#include <hip/hip_runtime.h>
#include <hip/hip_bf16.h>

#define N_ROWS 4096
#define H_DIM  512
#define V_DIM  50257
#define BM 128
#define BN 128
#define BK 64
#define NSTEP (H_DIM / BK)      // 8
#define VT_TOTAL 393            // ceil(V/BN)
#define V_PAD (VT_TOTAL * BN)   // 50304
#define NCHUNK 131              // 393 = 3*131 -> every block exactly 3 tiles
#define LOG2E 1.4426950408889634f
#define BUF0 0
#define BUF1 32768
#define LBASE 32768             // L tile (bf16) lives on BUF1 region

#define VMCNT8() asm volatile("s_waitcnt vmcnt(8)" ::: "memory")
#define VMCNT0() asm volatile("s_waitcnt vmcnt(0)" ::: "memory")
#define LGKM0()  asm volatile("s_waitcnt lgkmcnt(0)" ::: "memory")
#define BARRIER() __builtin_amdgcn_s_barrier()

typedef __attribute__((ext_vector_type(8))) short short8;
typedef __attribute__((ext_vector_type(4))) float f32x4;

static __device__ __forceinline__ unsigned short f2bf(float f) {
  unsigned u = __float_as_uint(f);
  u = (u + 0x7fffu + ((u >> 16) & 1u)) >> 16;   // RNE
  return (unsigned short)u;
}

static __device__ __forceinline__ void gload_lds16(const void* g, void* l) {
  __builtin_amdgcn_global_load_lds(
      (const __attribute__((address_space(1))) void*)g,
      (__attribute__((address_space(3))) void*)l, 16, 0, 0);
}

// ---------------- kernel A: fp32 -> bf16 conversion (W padded to V_PAD) ----
__global__ void convert_kernel(const float* __restrict__ X,
                               const float* __restrict__ W,
                               __hip_bfloat16* __restrict__ Xb,
                               __hip_bfloat16* __restrict__ Wb) {
  const long wtot8 = (long)V_PAD * H_DIM / 8;   // 3,219,456
  const long xtot8 = (long)N_ROWS * H_DIM / 8;  //   262,144
  long i = (long)blockIdx.x * blockDim.x + threadIdx.x;
  unsigned short o[8];
  if (i < wtot8) {
    long base = i * 8;
    long row = base >> 9;   // /512
    if (row < V_DIM) {
      const float4* s = (const float4*)(W + base);
      float4 a = s[0], b = s[1];
      o[0]=f2bf(a.x); o[1]=f2bf(a.y); o[2]=f2bf(a.z); o[3]=f2bf(a.w);
      o[4]=f2bf(b.x); o[5]=f2bf(b.y); o[6]=f2bf(b.z); o[7]=f2bf(b.w);
    } else {
      #pragma unroll
      for (int k = 0; k < 8; ++k) o[k] = 0;
    }
    *(short8*)(Wb + base) = *(const short8*)o;
  } else if (i < wtot8 + xtot8) {
    long base = (i - wtot8) * 8;
    const float4* s = (const float4*)(X + base);
    float4 a = s[0], b = s[1];
    o[0]=f2bf(a.x); o[1]=f2bf(a.y); o[2]=f2bf(a.z); o[3]=f2bf(a.w);
    o[4]=f2bf(b.x); o[5]=f2bf(b.y); o[6]=f2bf(b.z); o[7]=f2bf(b.w);
    *(short8*)(Xb + base) = *(const short8*)o;
  }
}

// stats update for one 16-col chunk (Lv includes bias)
template <bool GUARD>
static __device__ __forceinline__ void chunk_stats(
    const float (&Lraw)[16], const f32x4 (&T)[4], int gcol0,
    float& mlr, float& slr, float& mtr, float& str, float& ddr) {
  float Lv[16], Tv[16];
  #pragma unroll
  for (int k = 0; k < 16; ++k) {
    const bool ok = !GUARD || (gcol0 + k < V_DIM);
    Lv[k] = ok ? Lraw[k] : -1e30f;
    Tv[k] = ok ? T[k >> 2][k & 3] : -1e30f;
  }
  float g = Lv[0];
  #pragma unroll
  for (int k = 1; k < 16; ++k) g = fmaxf(g, Lv[k]);
  if (g > mlr + 12.f) { slr *= exp2f((mlr - g) * LOG2E); mlr = g; }
  float bl = mlr * LOG2E;
  float ss = 0.f;
  #pragma unroll
  for (int k = 0; k < 16; ++k) ss += exp2f(__builtin_fmaf(Lv[k], LOG2E, -bl));
  slr += ss;
  float gt = Tv[0];
  #pragma unroll
  for (int k = 1; k < 16; ++k) gt = fmaxf(gt, Tv[k]);
  if (gt > mtr + 12.f) {
    float sc = exp2f((mtr - gt) * LOG2E);
    str *= sc; ddr *= sc; mtr = gt;
  }
  float bt = mtr * LOG2E;
  float s2 = 0.f, d2 = 0.f;
  #pragma unroll
  for (int k = 0; k < 16; ++k) {
    float e = exp2f(__builtin_fmaf(Tv[k], LOG2E, -bt));
    s2 += e;
    d2 = __builtin_fmaf(e, Lv[k], d2);
  }
  str += s2; ddr += d2;
}

// streaming stats for one tile: 64 cols (4 chunks), 2-deep T pipeline.
// L is bf16 in LDS, row stride 256 B, XOR-swizzled.
template <bool GUARD>
static __device__ __forceinline__ void stream_tile(
    const float* __restrict__ targets, const char* __restrict__ Lrow,
    long growVD, int vbase, int cb0, int rsw, long tlim,
    float& mlr, float& slr, float& mtr, float& str, float& ddr) {
  f32x4 T0[4], T1[4];
  auto LOADT = [&](f32x4 (&D)[4], int i) {
    #pragma unroll
    for (int c = 0; c < 4; ++c) {
      long off = growVD + vbase + cb0 + i * 16 + c * 4;
      if (GUARD) off = off > tlim ? tlim : off;
      D[c] = *(const f32x4*)(targets + off);
    }
  };
  auto DOCHUNK = [&](const f32x4 (&T)[4], int i) {
    const int ob = (cb0 << 1) + (i << 5);
    short8 l0 = *(const short8*)(Lrow + ((ob) ^ rsw));
    short8 l1 = *(const short8*)(Lrow + ((ob + 16) ^ rsw));
    float Lraw[16];
    #pragma unroll
    for (int e = 0; e < 8; ++e) {
      Lraw[e]     = __uint_as_float(((unsigned)(unsigned short)l0[e]) << 16);
      Lraw[e + 8] = __uint_as_float(((unsigned)(unsigned short)l1[e]) << 16);
    }
    chunk_stats<GUARD>(Lraw, T, vbase + cb0 + i * 16, mlr, slr, mtr, str, ddr);
  };
  LOADT(T0, 0); LOADT(T1, 1);
  DOCHUNK(T0, 0);
  LOADT(T0, 2);
  DOCHUNK(T1, 1);
  LOADT(T1, 3);
  DOCHUNK(T0, 2);
  DOCHUNK(T1, 3);
}

// ---------------- kernel B: fused GEMM + online softmax stats -------------
// Grid (32, NCHUNK). Block 256 = 4 waves. Per tile:
//  (1) BK=64 dbuf K-loop with COUNTED vmcnt + raw s_barrier (loads stay in
//      flight across barriers); ks=7 prefetches next tile's k=0 into BUF0.
//  (2) dump acc+bias -> bf16 L tile on the BUF1 region (swizzled).
//  (3) streaming stats (targets + L), overlapping the in-flight k=0 stage.
__global__ __launch_bounds__(256, 2)
void fused_kernel(const __hip_bfloat16* __restrict__ Xb,
                  const __hip_bfloat16* __restrict__ Wb,
                  const float* __restrict__ bias,
                  const float* __restrict__ targets,
                  float* __restrict__ partials) {
  __shared__ __align__(16) char smem[65536];   // BUF0 | BUF1(=L bf16)

  const int tid  = threadIdx.x;
  const int lane = tid & 63;
  const int wid  = tid >> 6;
  const int wm   = wid >> 1;
  const int wn   = wid & 1;
  const int q    = lane >> 4;
  const int c15  = lane & 15;
  const int brow = blockIdx.x;
  const int chunk = blockIdx.y;

  float mlr = -1e30f, slr = 0.f, mtr = -1e30f, str = 0.f, ddr = 0.f;

  // staging precompute (linear LDS writes, pre-swizzled global source)
  const int srow8 = tid >> 3;                               // 0..31
  const int soff  = ((tid & 7) * 8) ^ ((srow8 & 7) * 8);    // elems in [0,64)
  const __hip_bfloat16* asrc = Xb + (long)(brow * BM + srow8) * H_DIM + soff;

  // fragment-read precompute
  const int rm      = (c15 & 7) << 4;          // byte XOR mask
  const int arow_b  = (wm * 64 + c15) * 128;   // + a*2048
  const int brow_b  = (wn * 64 + c15) * 128;   // + b*2048 (+16384 B-region)

  auto stage = [&](int bufb, const __hip_bfloat16* a_s,
                   const __hip_bfloat16* b_s, int kk) {
    #pragma unroll
    for (int i = 0; i < 4; ++i)
      gload_lds16(a_s + (long)i * 32 * H_DIM + kk,
                  smem + bufb + i * 4096 + tid * 16);
    #pragma unroll
    for (int i = 0; i < 4; ++i)
      gload_lds16(b_s + (long)i * 32 * H_DIM + kk,
                  smem + bufb + 16384 + i * 4096 + tid * 16);
  };

  // streaming-phase precompute
  const int srow  = tid >> 1;                  // 0..127
  const int shalf = tid & 1;
  const int cb0   = shalf * 64;
  const long grow   = (long)(brow * BM + srow);
  const long growVD = grow * V_DIM;
  const long tlim   = (long)N_ROWS * V_DIM - 4;
  const char* Lrow  = smem + LBASE + srow * 256;
  const int rsw     = (srow & 7) << 4;

  // prologue: stage first tile's k=0 into BUF0
  const __hip_bfloat16* bsrc = Wb + (long)(chunk * BN + srow8) * H_DIM + soff;
  stage(BUF0, asrc, bsrc, 0);

  #pragma unroll 1
  for (int vt = chunk; vt < VT_TOTAL; vt += NCHUNK) {
    const int vbase = vt * BN;
    const int v0 = vbase + wn * 64 + q * 4;
    const bool last = (vt + NCHUNK >= VT_TOTAL);
    const __hip_bfloat16* bsrc_next =
        Wb + (long)((vt + NCHUNK) * BN + srow8) * H_DIM + soff;

    f32x4 acc[4][4];
    #pragma unroll
    for (int a = 0; a < 4; ++a)
      #pragma unroll
      for (int b = 0; b < 4; ++b)
        acc[a][b] = (f32x4){0.f, 0.f, 0.f, 0.f};

    // ---- pipelined K-loop: counted vmcnt, raw barriers ----
    #pragma unroll
    for (int ks = 0; ks < NSTEP; ++ks) {
      const int cb = (ks & 1) ? BUF1 : BUF0;
      const int nb = cb ^ 32768;
      if (ks < NSTEP - 1)
        stage(nb, asrc, bsrc, (ks + 1) * BK);
      else if (!last)
        stage(nb, asrc, bsrc_next, 0);   // next tile k=0 -> BUF0

      if (ks == NSTEP - 1 && last) { VMCNT0(); } else { VMCNT8(); }
      BARRIER();

      #pragma unroll
      for (int s = 0; s < 2; ++s) {
        short8 xf[4], wf[4];
        #pragma unroll
        for (int a = 0; a < 4; ++a)
          xf[a] = *(const short8*)(smem + cb + arow_b + a * 2048 +
                                   ((s * 64 + q * 16) ^ rm));
        #pragma unroll
        for (int b = 0; b < 4; ++b)
          wf[b] = *(const short8*)(smem + cb + 16384 + brow_b + b * 2048 +
                                   ((s * 64 + q * 16) ^ rm));
        __builtin_amdgcn_s_setprio(1);
        #pragma unroll
        for (int a = 0; a < 4; ++a)
          #pragma unroll
          for (int b = 0; b < 4; ++b)
            acc[a][b] = __builtin_amdgcn_mfma_f32_16x16x32_bf16(
                wf[b], xf[a], acc[a][b], 0, 0, 0);
        __builtin_amdgcn_s_setprio(0);
      }
      LGKM0();
      BARRIER();
    }
    bsrc = bsrc_next;

    // ---- dump acc + bias -> bf16 L tile on BUF1 region (swizzled) ----
    f32x4 bp[4];
    #pragma unroll
    for (int b = 0; b < 4; ++b) {
      int bo = v0 + b * 16;
      bo = bo > (V_DIM - 4) ? (V_DIM - 4) : bo;
      bp[b] = *(const f32x4*)(bias + bo);
    }
    #pragma unroll
    for (int a = 0; a < 4; ++a) {
      const int row = wm * 64 + a * 16 + c15;      // row&7 == c15&7 -> XOR = rm
      char* rb = smem + LBASE + row * 256;
      #pragma unroll
      for (int b = 0; b < 4; ++b) {
        uint2 w;
        w.x = (unsigned)f2bf(acc[a][b][0] + bp[b][0]) |
              ((unsigned)f2bf(acc[a][b][1] + bp[b][1]) << 16);
        w.y = (unsigned)f2bf(acc[a][b][2] + bp[b][2]) |
              ((unsigned)f2bf(acc[a][b][3] + bp[b][3]) << 16);
        const int o = wn * 128 + b * 32 + q * 8;
        *(uint2*)(rb + (o ^ rm)) = w;
      }
    }
    LGKM0();
    BARRIER();

    // ---- streaming stats (k=0 stage of next tile in flight under this) ----
    if (vt == VT_TOTAL - 1)
      stream_tile<true >(targets, Lrow, growVD, vbase, cb0, rsw, tlim,
                         mlr, slr, mtr, str, ddr);
    else
      stream_tile<false>(targets, Lrow, growVD, vbase, cb0, rsw, tlim,
                         mlr, slr, mtr, str, ddr);
    LGKM0();
    BARRIER();   // L fully read before next tile's ks=0 stages over it
  }

  // merge the two halves of each row (lanes 2k / 2k+1)
  {
    float ml2 = __shfl_xor(mlr, 1);
    float sl2 = __shfl_xor(slr, 1);
    float mt2 = __shfl_xor(mtr, 1);
    float st2 = __shfl_xor(str, 1);
    float dd2 = __shfl_xor(ddr, 1);
    float nm = fmaxf(mlr, ml2);
    float slo = slr * exp2f((mlr - nm) * LOG2E) + sl2 * exp2f((ml2 - nm) * LOG2E);
    float nmt = fmaxf(mtr, mt2);
    float e1 = exp2f((mtr - nmt) * LOG2E);
    float e2 = exp2f((mt2 - nmt) * LOG2E);
    float sto = str * e1 + st2 * e2;
    float ddo = ddr * e1 + dd2 * e2;
    if (shalf == 0) {
      float* o = partials + (grow * NCHUNK + chunk) * 5;
      o[0] = nm; o[1] = slo; o[2] = nmt; o[3] = sto; o[4] = ddo;
    }
  }
}

// ---------------- kernel C: merge partials -> per-row loss ----------------
__global__ void rowloss_kernel(const float* __restrict__ partials,
                               float* __restrict__ rowloss) {
  int r = blockIdx.x * blockDim.x + threadIdx.x;
  if (r >= N_ROWS) return;
  const float* p = partials + (long)r * NCHUNK * 5;
  float ml = -1e30f, sl = 0.f, mt = -1e30f, st = 0.f, dd = 0.f;
  for (int c = 0; c < NCHUNK; ++c) {
    float ml2 = p[0], sl2 = p[1], mt2 = p[2], st2 = p[3], dd2 = p[4];
    p += 5;
    float nm = fmaxf(ml, ml2);
    sl = sl * exp2f((ml - nm) * LOG2E) + sl2 * exp2f((ml2 - nm) * LOG2E);
    ml = nm;
    float nmt = fmaxf(mt, mt2);
    float e1 = exp2f((mt - nmt) * LOG2E);
    float e2 = exp2f((mt2 - nmt) * LOG2E);
    st = st * e1 + st2 * e2;
    dd = dd * e1 + dd2 * e2;
    mt = nmt;
  }
  float lse = ml + logf(sl);
  rowloss[r] = lse - dd / st;
}

// ---------------- kernel D: final scalar reduce ---------------------------
__global__ void final_kernel(const float* __restrict__ rowloss,
                             float* __restrict__ out) {
  __shared__ float sm[4];
  float s = 0.f;
  for (int i = threadIdx.x; i < N_ROWS; i += 256) s += rowloss[i];
  #pragma unroll
  for (int off = 32; off > 0; off >>= 1) s += __shfl_down(s, off);
  if ((threadIdx.x & 63) == 0) sm[threadIdx.x >> 6] = s;
  __syncthreads();
  if (threadIdx.x == 0) out[0] = (sm[0] + sm[1] + sm[2] + sm[3]) * (1.0f / (float)N_ROWS);
}

extern "C" void kernel_launch(void* const* d_in, const int* in_sizes, int n_in,
                              void* d_out, int out_size, void* d_ws, size_t ws_size,
                              hipStream_t stream) {
  const float* x       = (const float*)d_in[0];   // [4096, 512]
  const float* targets = (const float*)d_in[1];   // [4096, 50257]
  const float* weight  = (const float*)d_in[2];   // [50257, 512]
  const float* bias    = (const float*)d_in[3];   // [50257]
  float* out = (float*)d_out;

  char* ws = (char*)d_ws;
  __hip_bfloat16* Wb = (__hip_bfloat16*)ws;                     // 51,511,296 B
  size_t off = (size_t)V_PAD * H_DIM * 2;
  __hip_bfloat16* Xb = (__hip_bfloat16*)(ws + off);             //  4,194,304 B
  off += (size_t)N_ROWS * H_DIM * 2;
  float* partials = (float*)(ws + off);                         // 10,731,520 B
  off += (size_t)N_ROWS * NCHUNK * 5 * sizeof(float);
  float* rowloss = (float*)(ws + off);                          //     16,384 B

  convert_kernel<<<13600, 256, 0, stream>>>(x, weight, Xb, Wb);
  dim3 grid(N_ROWS / BM, NCHUNK);
  fused_kernel<<<grid, 256, 0, stream>>>(Xb, Wb, bias, targets, partials);
  rowloss_kernel<<<N_ROWS / 256, 256, 0, stream>>>(partials, rowloss);
  final_kernel<<<1, 256, 0, stream>>>(rowloss, out);
}

// Round 10
// 537.299 us; speedup vs baseline: 1.0388x; 1.0388x over previous
//
#include <hip/hip_runtime.h>
#include <hip/hip_bf16.h>

#define N_ROWS 4096
#define H_DIM  512
#define V_DIM  50257
#define BM 128
#define BN 128
#define BK 64
#define NSTEP (H_DIM / BK)      // 8
#define VT_TOTAL 393            // ceil(V/BN)
#define V_PAD (VT_TOTAL * BN)   // 50304
#define NCHUNK 131              // 393 = 3*131 -> every block exactly 3 tiles
#define LOG2E 1.4426950408889634f
#define BUF0 0
#define BUF1 32768
#define LBASE 32768             // L tile (bf16) reuses BUF1 region

#define VMCNT4() asm volatile("s_waitcnt vmcnt(4)" ::: "memory")
#define VMCNT0() asm volatile("s_waitcnt vmcnt(0)" ::: "memory")
#define LGKM0()  asm volatile("s_waitcnt lgkmcnt(0)" ::: "memory")
#define BARRIER() __builtin_amdgcn_s_barrier()

typedef __attribute__((ext_vector_type(8))) short short8;
typedef __attribute__((ext_vector_type(4))) float f32x4;

static __device__ __forceinline__ unsigned short f2bf(float f) {
  unsigned u = __float_as_uint(f);
  u = (u + 0x7fffu + ((u >> 16) & 1u)) >> 16;   // RNE
  return (unsigned short)u;
}

static __device__ __forceinline__ void gload_lds16(const void* g, void* l) {
  __builtin_amdgcn_global_load_lds(
      (const __attribute__((address_space(1))) void*)g,
      (__attribute__((address_space(3))) void*)l, 16, 0, 0);
}

// ---------------- kernel A: fp32 -> bf16 conversion (W padded to V_PAD) ----
__global__ void convert_kernel(const float* __restrict__ X,
                               const float* __restrict__ W,
                               __hip_bfloat16* __restrict__ Xb,
                               __hip_bfloat16* __restrict__ Wb) {
  const long wtot8 = (long)V_PAD * H_DIM / 8;   // 3,219,456
  const long xtot8 = (long)N_ROWS * H_DIM / 8;  //   262,144
  long i = (long)blockIdx.x * blockDim.x + threadIdx.x;
  unsigned short o[8];
  if (i < wtot8) {
    long base = i * 8;
    long row = base >> 9;   // /512
    if (row < V_DIM) {
      const float4* s = (const float4*)(W + base);
      float4 a = s[0], b = s[1];
      o[0]=f2bf(a.x); o[1]=f2bf(a.y); o[2]=f2bf(a.z); o[3]=f2bf(a.w);
      o[4]=f2bf(b.x); o[5]=f2bf(b.y); o[6]=f2bf(b.z); o[7]=f2bf(b.w);
    } else {
      #pragma unroll
      for (int k = 0; k < 8; ++k) o[k] = 0;
    }
    *(short8*)(Wb + base) = *(const short8*)o;
  } else if (i < wtot8 + xtot8) {
    long base = (i - wtot8) * 8;
    const float4* s = (const float4*)(X + base);
    float4 a = s[0], b = s[1];
    o[0]=f2bf(a.x); o[1]=f2bf(a.y); o[2]=f2bf(a.z); o[3]=f2bf(a.w);
    o[4]=f2bf(b.x); o[5]=f2bf(b.y); o[6]=f2bf(b.z); o[7]=f2bf(b.w);
    *(short8*)(Xb + base) = *(const short8*)o;
  }
}

// stats update for one 16-col chunk (Lv includes bias)
template <bool GUARD>
static __device__ __forceinline__ void chunk_stats(
    const float (&Lraw)[16], const f32x4 (&T)[4], int gcol0,
    float& mlr, float& slr, float& mtr, float& str, float& ddr) {
  float Lv[16], Tv[16];
  #pragma unroll
  for (int k = 0; k < 16; ++k) {
    const bool ok = !GUARD || (gcol0 + k < V_DIM);
    Lv[k] = ok ? Lraw[k] : -1e30f;
    Tv[k] = ok ? T[k >> 2][k & 3] : -1e30f;
  }
  float g = Lv[0];
  #pragma unroll
  for (int k = 1; k < 16; ++k) g = fmaxf(g, Lv[k]);
  if (g > mlr + 12.f) { slr *= exp2f((mlr - g) * LOG2E); mlr = g; }
  float bl = mlr * LOG2E;
  float ss = 0.f;
  #pragma unroll
  for (int k = 0; k < 16; ++k) ss += exp2f(__builtin_fmaf(Lv[k], LOG2E, -bl));
  slr += ss;
  float gt = Tv[0];
  #pragma unroll
  for (int k = 1; k < 16; ++k) gt = fmaxf(gt, Tv[k]);
  if (gt > mtr + 12.f) {
    float sc = exp2f((mtr - gt) * LOG2E);
    str *= sc; ddr *= sc; mtr = gt;
  }
  float bt = mtr * LOG2E;
  float s2 = 0.f, d2 = 0.f;
  #pragma unroll
  for (int k = 0; k < 16; ++k) {
    float e = exp2f(__builtin_fmaf(Tv[k], LOG2E, -bt));
    s2 += e;
    d2 = __builtin_fmaf(e, Lv[k], d2);
  }
  str += s2; ddr += d2;
}

// streaming stats for one tile: thread owns (row, 32-col quarter) = 2 chunks.
// L is bf16 in LDS, row stride 256 B, XOR-swizzled by (row&7)<<4.
template <bool GUARD>
static __device__ __forceinline__ void stream_tile(
    const float* __restrict__ targets, const char* __restrict__ Lrow,
    long growVD, int vbase, int q32, int rsw, long tlim,
    float& mlr, float& slr, float& mtr, float& str, float& ddr) {
  f32x4 T0[4], T1[4];
  #pragma unroll
  for (int c = 0; c < 4; ++c) {
    long off = growVD + vbase + q32 + c * 4;
    if (GUARD) off = off > tlim ? tlim : off;
    T0[c] = *(const f32x4*)(targets + off);
  }
  #pragma unroll
  for (int c = 0; c < 4; ++c) {
    long off = growVD + vbase + q32 + 16 + c * 4;
    if (GUARD) off = off > tlim ? tlim : off;
    T1[c] = *(const f32x4*)(targets + off);
  }
  #pragma unroll
  for (int i = 0; i < 2; ++i) {
    const int ob = (q32 << 1) + (i << 5);
    short8 l0 = *(const short8*)(Lrow + ((ob) ^ rsw));
    short8 l1 = *(const short8*)(Lrow + ((ob + 16) ^ rsw));
    float Lraw[16];
    #pragma unroll
    for (int e = 0; e < 8; ++e) {
      Lraw[e]     = __uint_as_float(((unsigned)(unsigned short)l0[e]) << 16);
      Lraw[e + 8] = __uint_as_float(((unsigned)(unsigned short)l1[e]) << 16);
    }
    if (i == 0)
      chunk_stats<GUARD>(Lraw, T0, vbase + q32,      mlr, slr, mtr, str, ddr);
    else
      chunk_stats<GUARD>(Lraw, T1, vbase + q32 + 16, mlr, slr, mtr, str, ddr);
  }
}

// ---------------- kernel B: fused GEMM + online softmax stats -------------
// Grid (32, NCHUNK). Block 512 = 8 waves (2x4 over the 128x128 tile) ->
// 2 blocks/CU = 4 waves/SIMD. Per tile: counted-vmcnt dbuf K-loop (BK=64),
// acc+bias -> bf16 L on BUF1, streaming stats (4 threads per row).
__global__ __launch_bounds__(512, 4)
void fused_kernel(const __hip_bfloat16* __restrict__ Xb,
                  const __hip_bfloat16* __restrict__ Wb,
                  const float* __restrict__ bias,
                  const float* __restrict__ targets,
                  float* __restrict__ partials) {
  __shared__ __align__(16) char smem[65536];   // BUF0 | BUF1(=L bf16)

  const int tid  = threadIdx.x;
  const int lane = tid & 63;
  const int wid  = tid >> 6;
  const int wm   = wid >> 2;          // 0..1 (64 x-rows each)
  const int wn   = wid & 3;           // 0..3 (32 vocab cols each)
  const int q    = lane >> 4;
  const int c15  = lane & 15;
  const int brow = blockIdx.x;
  const int chunk = blockIdx.y;

  float mlr = -1e30f, slr = 0.f, mtr = -1e30f, str = 0.f, ddr = 0.f;

  // staging precompute: thread t writes LDS linearly at (site i)*8192+t*16;
  // row = i*64 + (t>>3), 16B-unit = t&7; source pre-swizzled by row&7.
  const int srow8 = tid >> 3;                               // 0..63
  const int soff  = ((tid & 7) ^ (srow8 & 7)) * 8;          // elems in [0,64)
  const __hip_bfloat16* asrc = Xb + (long)(brow * BM + srow8) * H_DIM + soff;

  // fragment-read precompute
  const int rm      = (c15 & 7) << 4;          // byte XOR mask
  const int arow_b  = (wm * 64 + c15) * 128;   // + a*2048
  const int brow_b  = (wn * 32 + c15) * 128;   // + b*2048 (+16384 B-region)

  auto stage = [&](int bufb, const __hip_bfloat16* a_s,
                   const __hip_bfloat16* b_s, int kk) {
    #pragma unroll
    for (int i = 0; i < 2; ++i)
      gload_lds16(a_s + (long)i * 64 * H_DIM + kk,
                  smem + bufb + i * 8192 + tid * 16);
    #pragma unroll
    for (int i = 0; i < 2; ++i)
      gload_lds16(b_s + (long)i * 64 * H_DIM + kk,
                  smem + bufb + 16384 + i * 8192 + tid * 16);
  };

  // streaming-phase precompute: row = tid>>2, quarter = tid&3 (32 cols)
  const int srow  = tid >> 2;                  // 0..127
  const int quart = tid & 3;
  const int q32   = quart * 32;
  const long grow   = (long)(brow * BM + srow);
  const long growVD = grow * V_DIM;
  const long tlim   = (long)N_ROWS * V_DIM - 4;
  const char* Lrow  = smem + LBASE + srow * 256;
  const int rsw     = (srow & 7) << 4;

  // prologue: stage first tile's k=0 into BUF0
  const __hip_bfloat16* bsrc = Wb + (long)(chunk * BN + srow8) * H_DIM + soff;
  stage(BUF0, asrc, bsrc, 0);

  #pragma unroll 1
  for (int vt = chunk; vt < VT_TOTAL; vt += NCHUNK) {
    const int vbase = vt * BN;
    const int v0 = vbase + wn * 32 + q * 4;      // + b*16 + j
    const bool last = (vt + NCHUNK >= VT_TOTAL);
    const __hip_bfloat16* bsrc_next =
        Wb + (long)((vt + NCHUNK) * BN + srow8) * H_DIM + soff;

    f32x4 acc[4][2];
    #pragma unroll
    for (int a = 0; a < 4; ++a)
      #pragma unroll
      for (int b = 0; b < 2; ++b)
        acc[a][b] = (f32x4){0.f, 0.f, 0.f, 0.f};

    // ---- pipelined K-loop: counted vmcnt, raw barriers ----
    #pragma unroll
    for (int ks = 0; ks < NSTEP; ++ks) {
      const int cb = (ks & 1) ? BUF1 : BUF0;
      const int nb = cb ^ 32768;
      if (ks < NSTEP - 1)
        stage(nb, asrc, bsrc, (ks + 1) * BK);
      else if (!last)
        stage(nb, asrc, bsrc_next, 0);   // next tile k=0 -> BUF0

      if (ks == NSTEP - 1 && last) { VMCNT0(); } else { VMCNT4(); }
      BARRIER();

      #pragma unroll
      for (int s = 0; s < 2; ++s) {
        short8 xf[4], wf[2];
        #pragma unroll
        for (int a = 0; a < 4; ++a)
          xf[a] = *(const short8*)(smem + cb + arow_b + a * 2048 +
                                   ((s * 64 + q * 16) ^ rm));
        #pragma unroll
        for (int b = 0; b < 2; ++b)
          wf[b] = *(const short8*)(smem + cb + 16384 + brow_b + b * 2048 +
                                   ((s * 64 + q * 16) ^ rm));
        #pragma unroll
        for (int a = 0; a < 4; ++a)
          #pragma unroll
          for (int b = 0; b < 2; ++b)
            acc[a][b] = __builtin_amdgcn_mfma_f32_16x16x32_bf16(
                wf[b], xf[a], acc[a][b], 0, 0, 0);
      }
      LGKM0();
      BARRIER();
    }
    bsrc = bsrc_next;

    // ---- dump acc + bias -> bf16 L tile on BUF1 region (swizzled) ----
    f32x4 bp[2];
    #pragma unroll
    for (int b = 0; b < 2; ++b) {
      int bo = v0 + b * 16;
      bo = bo > (V_DIM - 4) ? (V_DIM - 4) : bo;
      bp[b] = *(const f32x4*)(bias + bo);
    }
    #pragma unroll
    for (int a = 0; a < 4; ++a) {
      const int row = wm * 64 + a * 16 + c15;      // row&7 == c15&7 -> XOR = rm
      char* rb = smem + LBASE + row * 256;
      #pragma unroll
      for (int b = 0; b < 2; ++b) {
        uint2 w;
        w.x = (unsigned)f2bf(acc[a][b][0] + bp[b][0]) |
              ((unsigned)f2bf(acc[a][b][1] + bp[b][1]) << 16);
        w.y = (unsigned)f2bf(acc[a][b][2] + bp[b][2]) |
              ((unsigned)f2bf(acc[a][b][3] + bp[b][3]) << 16);
        const int o = wn * 64 + b * 32 + q * 8;
        *(uint2*)(rb + (o ^ rm)) = w;
      }
    }
    LGKM0();
    BARRIER();

    // ---- streaming stats (k=0 stage of next tile in flight under this) ----
    if (vt == VT_TOTAL - 1)
      stream_tile<true >(targets, Lrow, growVD, vbase, q32, rsw, tlim,
                         mlr, slr, mtr, str, ddr);
    else
      stream_tile<false>(targets, Lrow, growVD, vbase, q32, rsw, tlim,
                         mlr, slr, mtr, str, ddr);
    LGKM0();
    BARRIER();   // L fully read before next tile's ks=0 stages over it
  }

  // merge the four quarters of each row (lane bits 0,1)
  #pragma unroll
  for (int off = 1; off <= 2; off <<= 1) {
    float ml2 = __shfl_xor(mlr, off);
    float sl2 = __shfl_xor(slr, off);
    float mt2 = __shfl_xor(mtr, off);
    float st2 = __shfl_xor(str, off);
    float dd2 = __shfl_xor(ddr, off);
    float nm = fmaxf(mlr, ml2);
    slr = slr * exp2f((mlr - nm) * LOG2E) + sl2 * exp2f((ml2 - nm) * LOG2E);
    mlr = nm;
    float nmt = fmaxf(mtr, mt2);
    float e1 = exp2f((mtr - nmt) * LOG2E);
    float e2 = exp2f((mt2 - nmt) * LOG2E);
    str = str * e1 + st2 * e2;
    ddr = ddr * e1 + dd2 * e2;
    mtr = nmt;
  }
  if (quart == 0) {
    float* o = partials + (grow * NCHUNK + chunk) * 5;
    o[0] = mlr; o[1] = slr; o[2] = mtr; o[3] = str; o[4] = ddr;
  }
}

// ---------------- kernel C: merge partials -> per-row loss ----------------
__global__ void rowloss_kernel(const float* __restrict__ partials,
                               float* __restrict__ rowloss) {
  int r = blockIdx.x * blockDim.x + threadIdx.x;
  if (r >= N_ROWS) return;
  const float* p = partials + (long)r * NCHUNK * 5;
  float ml = -1e30f, sl = 0.f, mt = -1e30f, st = 0.f, dd = 0.f;
  for (int c = 0; c < NCHUNK; ++c) {
    float ml2 = p[0], sl2 = p[1], mt2 = p[2], st2 = p[3], dd2 = p[4];
    p += 5;
    float nm = fmaxf(ml, ml2);
    sl = sl * exp2f((ml - nm) * LOG2E) + sl2 * exp2f((ml2 - nm) * LOG2E);
    ml = nm;
    float nmt = fmaxf(mt, mt2);
    float e1 = exp2f((mt - nmt) * LOG2E);
    float e2 = exp2f((mt2 - nmt) * LOG2E);
    st = st * e1 + st2 * e2;
    dd = dd * e1 + dd2 * e2;
    mt = nmt;
  }
  float lse = ml + logf(sl);
  rowloss[r] = lse - dd / st;
}

// ---------------- kernel D: final scalar reduce ---------------------------
__global__ void final_kernel(const float* __restrict__ rowloss,
                             float* __restrict__ out) {
  __shared__ float sm[4];
  float s = 0.f;
  for (int i = threadIdx.x; i < N_ROWS; i += 256) s += rowloss[i];
  #pragma unroll
  for (int off = 32; off > 0; off >>= 1) s += __shfl_down(s, off);
  if ((threadIdx.x & 63) == 0) sm[threadIdx.x >> 6] = s;
  __syncthreads();
  if (threadIdx.x == 0) out[0] = (sm[0] + sm[1] + sm[2] + sm[3]) * (1.0f / (float)N_ROWS);
}

extern "C" void kernel_launch(void* const* d_in, const int* in_sizes, int n_in,
                              void* d_out, int out_size, void* d_ws, size_t ws_size,
                              hipStream_t stream) {
  const float* x       = (const float*)d_in[0];   // [4096, 512]
  const float* targets = (const float*)d_in[1];   // [4096, 50257]
  const float* weight  = (const float*)d_in[2];   // [50257, 512]
  const float* bias    = (const float*)d_in[3];   // [50257]
  float* out = (float*)d_out;

  char* ws = (char*)d_ws;
  __hip_bfloat16* Wb = (__hip_bfloat16*)ws;                     // 51,511,296 B
  size_t off = (size_t)V_PAD * H_DIM * 2;
  __hip_bfloat16* Xb = (__hip_bfloat16*)(ws + off);             //  4,194,304 B
  off += (size_t)N_ROWS * H_DIM * 2;
  float* partials = (float*)(ws + off);                         // 10,731,520 B
  off += (size_t)N_ROWS * NCHUNK * 5 * sizeof(float);
  float* rowloss = (float*)(ws + off);                          //     16,384 B

  convert_kernel<<<13600, 256, 0, stream>>>(x, weight, Xb, Wb);
  dim3 grid(N_ROWS / BM, NCHUNK);
  fused_kernel<<<grid, 512, 0, stream>>>(Xb, Wb, bias, targets, partials);
  rowloss_kernel<<<N_ROWS / 256, 256, 0, stream>>>(partials, rowloss);
  final_kernel<<<1, 256, 0, stream>>>(rowloss, out);
}